// Round 14
// baseline (272.451 us; speedup 1.0000x reference)
//
#include <hip/hip_runtime.h>
#include <math.h>
#include <float.h>

#define BATCH 8
#define HIGH  256
#define LOWR  64
#define NN    4096          // LOWR*LOWR
#define HIDC  16
#define C1    64
#define NSL   8             // j-slices in kNN scan (512 j each)

// workspace layout (floats) — footprint identical to the validated layout
#define OFF_XL   0                               // DEAD (down fused into conv1)
#define OFF_H1   (OFF_XL  + BATCH*NN)            // 2.097M floats; reused after conv2:
                                                 //   [0 .. 1,048,575]         cand_i (4 MB, NSL=8)
                                                 //   [1,048,576 .. 1,835,007] bf16 hi/mid/lo splits
                                                 //   [1,835,008 .. 1,867,775] nsq (= -sq)
#define OFF_H    (OFF_H1  + BATCH*C1*NN)         // node-major [B*N][16]
#define OFF_SQ   (OFF_H   + BATCH*NN*HIDC)       // 0.5*|h|^2 per node
#define OFF_XP   (OFF_SQ  + BATCH*NN)
#define OFF_ASR  (OFF_XP  + BATCH*NN*HIDC)
#define OFF_ADT  (OFF_ASR + BATCH*NN*4)
#define OFF_P    (OFF_ADT + BATCH*NN*4)          // DEAD (update fused into gat2, R10)
#define OFF_OL   (OFF_P   + BATCH*NN*HIDC)

typedef __attribute__((ext_vector_type(8)))  short bf16x8;
typedef __attribute__((ext_vector_type(16))) float f32x16;

// identical-arithmetic dot used by k_gat2 (exact fp32 re-score of the pool —
// final selection semantics unchanged from the validated kernel)
__device__ __forceinline__ float dot16m(const float ni[16], float4 a0, float4 a1,
                                        float4 a2, float4 a3, float hs) {
    return ni[0]*a0.x + ni[1]*a0.y + ni[2]*a0.z + ni[3]*a0.w
         + ni[4]*a1.x + ni[5]*a1.y + ni[6]*a1.z + ni[7]*a1.w
         + ni[8]*a2.x + ni[9]*a2.y + ni[10]*a2.z + ni[11]*a2.w
         + ni[12]*a3.x + ni[13]*a3.y + ni[14]*a3.z + ni[15]*a3.w
         - hs;
}

// ---- fused: bilinear downsample 256->64 (tile+halo in LDS) + conv3x3 1->64 --
// (validated R12; unchanged)
__launch_bounds__(512)
__global__ void k_dconv1(const float* __restrict__ x, const float* __restrict__ W1,
                         const float* __restrict__ b1, const float* __restrict__ g1,
                         const float* __restrict__ be1, const float* __restrict__ m1,
                         const float* __restrict__ v1, float* __restrict__ h1) {
    __shared__ float sW[576];
    __shared__ float sb[64], sg[64], sbe[64], sm[64], sv[64];
    __shared__ float sxl[4][66];
    int tid = threadIdx.x;
    for (int k = tid; k < 576; k += 512) sW[k] = W1[k];
    if (tid < 64) {
        sb[tid] = b1[tid]; sg[tid] = g1[tid]; sbe[tid] = be1[tid];
        sm[tid] = m1[tid]; sv[tid] = v1[tid];
    }
    int blk = blockIdx.x;                 // 8 batches * 32 y-tiles
    int b = blk >> 5, ytile = blk & 31;
    if (tid < 264) {                      // 4 rows x 66 cols (incl. halo)
        int tr = tid / 66, tc = tid - tr * 66;
        int oy = ytile * 2 - 1 + tr, ox = tc - 1;
        float val = 0.f;
        if (oy >= 0 && oy < 64 && ox >= 0 && ox < 64) {
            const float* xb = x + b * HIGH * HIGH;
            float cy = 4.f * oy + 1.5f, cx = 4.f * ox + 1.5f;
            float wy[8], wx[8], sy = 0.f, sx = 0.f;
#pragma unroll
            for (int k = 0; k < 8; k++) {
                int iy = 4 * oy - 2 + k;
                float w = 1.f - fabsf((float)iy - cy) * 0.25f;
                if (iy < 0 || iy >= HIGH) w = 0.f;
                wy[k] = w; sy += w;
                int ix = 4 * ox - 2 + k;
                float v = 1.f - fabsf((float)ix - cx) * 0.25f;
                if (ix < 0 || ix >= HIGH) v = 0.f;
                wx[k] = v; sx += v;
            }
            float acc = 0.f;
#pragma unroll
            for (int ky = 0; ky < 8; ky++) {
                if (wy[ky] == 0.f) continue;
                int iy = 4 * oy - 2 + ky;
                float rowacc = 0.f;
#pragma unroll
                for (int kx = 0; kx < 8; kx++) {
                    if (wx[kx] == 0.f) continue;
                    int ix = 4 * ox - 2 + kx;
                    rowacc += wx[kx] * xb[iy * HIGH + ix];
                }
                acc += wy[ky] * rowacc;
            }
            val = acc / (sy * sx);
        }
        sxl[tr][tc] = val;
    }
    __syncthreads();
    int pix = tid & 127, row = pix >> 6, col = pix & 63;
    float t00 = sxl[row    ][col], t01 = sxl[row    ][col + 1], t02 = sxl[row    ][col + 2];
    float t10 = sxl[row + 1][col], t11 = sxl[row + 1][col + 1], t12 = sxl[row + 1][col + 2];
    float t20 = sxl[row + 2][col], t21 = sxl[row + 2][col + 1], t22 = sxl[row + 2][col + 2];
    int y = ytile * 2 + row;
    long base = (long)b * C1 * NN + (long)y * 64 + col;
#pragma unroll
    for (int it = 0; it < 16; it++) {
        int co = it * 4 + (tid >> 7);     // wave-uniform
        const float* w = &sW[co * 9];
        float acc = 0.f;                  // tap order identical to unfused conv1
        acc += w[0] * t00; acc += w[1] * t01; acc += w[2] * t02;
        acc += w[3] * t10; acc += w[4] * t11; acc += w[5] * t12;
        acc += w[6] * t20; acc += w[7] * t21; acc += w[8] * t22;
        acc += sb[co];
        float sc = sg[co] / sqrtf(sv[co] + 1e-5f);
        acc = (acc - sm[co]) * sc + sbe[co];
        h1[base + (long)co * NN] = fmaxf(acc, 0.f);
    }
}

// ------- conv3x3 64->16 + BN + relu, fused: h (node-major), sq, xp, asr, adt -
// (validated R7; unchanged)
__launch_bounds__(512)
__global__ void k_conv2(const float* __restrict__ h1, const float* __restrict__ W2,
                        const float* __restrict__ b2, const float* __restrict__ g2,
                        const float* __restrict__ be2, const float* __restrict__ m2,
                        const float* __restrict__ v2, const float* __restrict__ Wg,
                        const float* __restrict__ a_src, const float* __restrict__ a_dst,
                        float* __restrict__ h, float* __restrict__ sq,
                        float* __restrict__ xp, float* __restrict__ asr,
                        float* __restrict__ adt) {
    __shared__ float sW2t[576 * 16];    // [ci*9+tap][o]
    __shared__ float sWg[256];
    __shared__ float sA[32];
    __shared__ float accH[3][128][17];  // partials from quarters 1..3 (17-pad)
    int tid = threadIdx.x;
    for (int k = tid; k < 9216; k += 512) {          // coalesced global read, scatter to LDS
        int o = k / 576, ct = k - o * 576;
        sW2t[ct * 16 + o] = W2[k];
    }
    if (tid < 256) sWg[tid] = Wg[tid];
    if (tid < 16) { sA[tid] = a_src[tid]; sA[16 + tid] = a_dst[tid]; }
    __syncthreads();
    int blk = blockIdx.x;                 // 8 batches * 32 y-tiles
    int b = blk >> 5, ytile = blk & 31;
    int q = tid >> 7;                     // ci quarter 0..3
    int sub = tid & 127;
    int ty = sub >> 6, x = sub & 63, y = ytile * 2 + ty;
    float acc[16];
#pragma unroll
    for (int o = 0; o < 16; o++) acc[o] = 0.f;
    const float* hb = h1 + (long)b * C1 * NN + (long)q * 16 * NN;
    for (int ci = 0; ci < 16; ci++) {
        const float* plane = hb + ci * NN;
#pragma unroll
        for (int dy = -1; dy <= 1; dy++) {
            int yy = y + dy; bool oky = (yy >= 0 && yy < 64);
#pragma unroll
            for (int dx = -1; dx <= 1; dx++) {
                int xx = x + dx;
                float v = (oky && xx >= 0 && xx < 64) ? plane[yy * 64 + xx] : 0.f;
                int ct = (q * 16 + ci) * 9 + (dy + 1) * 3 + (dx + 1);
                const float4* wr = (const float4*)&sW2t[ct * 16];
                float4 w0 = wr[0], w1 = wr[1], w2 = wr[2], w3 = wr[3];
                acc[0] += v * w0.x; acc[1] += v * w0.y; acc[2] += v * w0.z; acc[3] += v * w0.w;
                acc[4] += v * w1.x; acc[5] += v * w1.y; acc[6] += v * w1.z; acc[7] += v * w1.w;
                acc[8] += v * w2.x; acc[9] += v * w2.y; acc[10]+= v * w2.z; acc[11]+= v * w2.w;
                acc[12]+= v * w3.x; acc[13]+= v * w3.y; acc[14]+= v * w3.z; acc[15]+= v * w3.w;
            }
        }
    }
    if (q != 0) {
        float* dst = &accH[q - 1][sub][0];
#pragma unroll
        for (int o = 0; o < 16; o++) dst[o] = acc[o];
    }
    __syncthreads();
    if (q != 0) return;
#pragma unroll
    for (int qq = 0; qq < 3; qq++) {
        const float* src = &accH[qq][sub][0];
#pragma unroll
        for (int o = 0; o < 16; o++) acc[o] += src[o];
    }
    int n = y * 64 + x;
    long node = (long)b * NN + n;
    float nodev[16], sqv = 0.f;
#pragma unroll
    for (int o = 0; o < 16; o++) {
        float a = acc[o] + b2[o];
        float sc = g2[o] / sqrtf(v2[o] + 1e-5f);
        a = (a - m2[o]) * sc + be2[o];
        a = fmaxf(a, 0.f);
        nodev[o] = a; sqv += a * a;
        h[node * 16 + o] = a;
    }
    sq[node] = 0.5f * sqv;                // pre-scaled: scan/merge use dot - 0.5|j|^2
    float xpv[16];
#pragma unroll
    for (int o = 0; o < 16; o++) {
        float a = 0.f;
#pragma unroll
        for (int c = 0; c < 16; c++) a += sWg[o * 16 + c] * nodev[c];
        xpv[o] = a;
        xp[node * 16 + o] = a;
    }
#pragma unroll
    for (int hh = 0; hh < 4; hh++) {
        float as = 0.f, ad = 0.f;
#pragma unroll
        for (int f = 0; f < 4; f++) {
            as += xpv[hh * 4 + f] * sA[hh * 4 + f];
            ad += xpv[hh * 4 + f] * sA[16 + hh * 4 + f];
        }
        asr[node * 4 + hh] = as;
        adt[node * 4 + hh] = ad;
    }
}

// ------- error-free 3-way bf16 split of h: h = hi + mid + lo + O(2^-27) -----
__device__ __forceinline__ ushort f2bf(float f) {
    unsigned u = __float_as_uint(f);
    return (ushort)((u + 0x7FFFu + ((u >> 16) & 1u)) >> 16);
}
__device__ __forceinline__ float bf2f(ushort h) {
    return __uint_as_float(((unsigned)h) << 16);
}
__launch_bounds__(256)
__global__ void k_split(const float* __restrict__ h, const float* __restrict__ sq,
                        ushort* __restrict__ hHi, ushort* __restrict__ hMid,
                        ushort* __restrict__ hLo, float* __restrict__ nsq) {
    long t = (long)blockIdx.x * 256 + threadIdx.x;   // node 0..32767
    nsq[t] = -sq[t];                                  // negated for MFMA C-init
    const float4* hp = (const float4*)&h[t * 16];
    float4 v0 = hp[0], v1 = hp[1], v2 = hp[2], v3 = hp[3];
    float v[16] = { v0.x,v0.y,v0.z,v0.w, v1.x,v1.y,v1.z,v1.w,
                    v2.x,v2.y,v2.z,v2.w, v3.x,v3.y,v3.z,v3.w };
    unsigned wh[8], wm[8], wl[8];
#pragma unroll
    for (int p = 0; p < 8; p++) {
        unsigned packh = 0, packm = 0, packl = 0;
#pragma unroll
        for (int e = 0; e < 2; e++) {
            float f = v[p * 2 + e];
            ushort hi = f2bf(f);
            float t1 = f - bf2f(hi);
            ushort mi = f2bf(t1);
            float t2 = t1 - bf2f(mi);
            ushort lo = f2bf(t2);
            packh |= ((unsigned)hi) << (16 * e);
            packm |= ((unsigned)mi) << (16 * e);
            packl |= ((unsigned)lo) << (16 * e);
        }
        wh[p] = packh; wm[p] = packm; wl[p] = packl;
    }
    uint4* dh = (uint4*)&hHi[t * 16];
    uint4* dm = (uint4*)&hMid[t * 16];
    uint4* dl = (uint4*)&hLo[t * 16];
    dh[0] = make_uint4(wh[0], wh[1], wh[2], wh[3]);
    dh[1] = make_uint4(wh[4], wh[5], wh[6], wh[7]);
    dm[0] = make_uint4(wm[0], wm[1], wm[2], wm[3]);
    dm[1] = make_uint4(wm[4], wm[5], wm[6], wm[7]);
    dl[0] = make_uint4(wl[0], wl[1], wl[2], wl[3]);
    dl[1] = make_uint4(wl[4], wl[5], wl[6], wl[7]);
}

// --- shared tile-score routine: MUST be bit-identical between pass 1/2 ------
__device__ __forceinline__ void tile_scores(const ushort* __restrict__ hHi,
        const ushort* __restrict__ hMid, const ushort* __restrict__ hLo,
        const float* __restrict__ nsq, long bN, int j0, int ln31, int koff,
        int rbase, int i0w, bf16x8 bi_h, bf16x8 bi_m, bf16x8 bi_l,
        float scv[16]) {
    int jr = j0 + ln31;
    bf16x8 aj_h = *(const bf16x8*)&hHi [(bN + jr) * 16 + koff];
    bf16x8 aj_m = *(const bf16x8*)&hMid[(bN + jr) * 16 + koff];
    bf16x8 aj_l = *(const bf16x8*)&hLo [(bN + jr) * 16 + koff];
    float4 q0 = *(const float4*)&nsq[bN + j0 +  0 + rbase];
    float4 q1 = *(const float4*)&nsq[bN + j0 +  8 + rbase];
    float4 q2 = *(const float4*)&nsq[bN + j0 + 16 + rbase];
    float4 q3 = *(const float4*)&nsq[bN + j0 + 24 + rbase];
    f32x16 acc;
    acc[0]  = q0.x; acc[1]  = q0.y; acc[2]  = q0.z; acc[3]  = q0.w;
    acc[4]  = q1.x; acc[5]  = q1.y; acc[6]  = q1.z; acc[7]  = q1.w;
    acc[8]  = q2.x; acc[9]  = q2.y; acc[10] = q2.z; acc[11] = q2.w;
    acc[12] = q3.x; acc[13] = q3.y; acc[14] = q3.z; acc[15] = q3.w;
    acc = __builtin_amdgcn_mfma_f32_32x32x16_bf16(aj_h, bi_h, acc, 0, 0, 0);
    acc = __builtin_amdgcn_mfma_f32_32x32x16_bf16(aj_h, bi_m, acc, 0, 0, 0);
    acc = __builtin_amdgcn_mfma_f32_32x32x16_bf16(aj_m, bi_h, acc, 0, 0, 0);
    acc = __builtin_amdgcn_mfma_f32_32x32x16_bf16(aj_h, bi_l, acc, 0, 0, 0);
    acc = __builtin_amdgcn_mfma_f32_32x32x16_bf16(aj_l, bi_h, acc, 0, 0, 0);
    acc = __builtin_amdgcn_mfma_f32_32x32x16_bf16(aj_m, bi_m, acc, 0, 0, 0);
#pragma unroll
    for (int rr = 0; rr < 16; rr++) scv[rr] = acc[rr];
    if (j0 == i0w) {                       // wave-uniform: diagonal tile, mask self
#pragma unroll
        for (int rr = 0; rr < 16; rr++) {
            int r = (rr & 3) + 8 * (rr >> 2) + rbase;
            if (r == ln31) scv[rr] = -FLT_MAX;
        }
    }
}

// --- sorting-network primitives (compare-exchange = max/min pair: exact
// multiset preservation, fully unrolled constant indexing) ------------------
#define CEX(a, b) { float ce_hi = fmaxf(a, b), ce_lo = fminf(a, b); (a) = ce_hi; (b) = ce_lo; }
// Batcher odd-even mergesort, 8 values descending (19 CE)
__device__ __forceinline__ void sort8d(float v[8]) {
    CEX(v[0],v[1]); CEX(v[2],v[3]); CEX(v[4],v[5]); CEX(v[6],v[7]);
    CEX(v[0],v[2]); CEX(v[1],v[3]); CEX(v[4],v[6]); CEX(v[5],v[7]);
    CEX(v[1],v[2]); CEX(v[5],v[6]);
    CEX(v[0],v[4]); CEX(v[1],v[5]); CEX(v[2],v[6]); CEX(v[3],v[7]);
    CEX(v[2],v[4]); CEX(v[3],v[5]);
    CEX(v[1],v[2]); CEX(v[3],v[4]); CEX(v[5],v[6]);
}
// bitonic 8-sequence -> sorted descending (12 CE)
__device__ __forceinline__ void bsort8d(float v[8]) {
    CEX(v[0],v[4]); CEX(v[1],v[5]); CEX(v[2],v[6]); CEX(v[3],v[7]);
    CEX(v[0],v[2]); CEX(v[1],v[3]); CEX(v[4],v[6]); CEX(v[5],v[7]);
    CEX(v[0],v[1]); CEX(v[2],v[3]); CEX(v[4],v[5]); CEX(v[6],v[7]);
}
// compare-exchange with carried id under (score desc, id asc) total order
#define CEX2(sa, ia, sb, ib) { \
    bool sw2 = ((sb) > (sa)) || ((sb) == (sa) && (ib) < (ia)); \
    float th2 = sw2 ? (sb) : (sa); float tl2 = sw2 ? (sa) : (sb); \
    int   ih2 = sw2 ? (ib) : (ia); int   il2 = sw2 ? (ia) : (ib); \
    (sa) = th2; (sb) = tl2; (ia) = ih2; (ib) = il2; }
// bitonic 8 -> sorted by (score desc, id asc), ids carried (12 CE2)
__device__ __forceinline__ void bsort8d_id(float v[8], int id[8]) {
    CEX2(v[0],id[0],v[4],id[4]); CEX2(v[1],id[1],v[5],id[5]);
    CEX2(v[2],id[2],v[6],id[6]); CEX2(v[3],id[3],v[7],id[7]);
    CEX2(v[0],id[0],v[2],id[2]); CEX2(v[1],id[1],v[3],id[3]);
    CEX2(v[4],id[4],v[6],id[6]); CEX2(v[5],id[5],v[7],id[7]);
    CEX2(v[0],id[0],v[1],id[1]); CEX2(v[2],id[2],v[3],id[3]);
    CEX2(v[4],id[4],v[5],id[5]); CEX2(v[6],id[6],v[7],id[7]);
}

// --------- kNN scan, two-pass scores-only selection (validated R6-R9) --------
// At structural floor per R9 falsifier: ~89% pipe-busy, selection networks at
// the CE lower bound, occupancy lever exhausted. NOT touched since R9.
__global__ __attribute__((amdgpu_waves_per_eu(4, 8))) __launch_bounds__(256)
void k_scan(const ushort* __restrict__ hHi, const ushort* __restrict__ hMid,
            const ushort* __restrict__ hLo, const float* __restrict__ nsq,
            uint4* __restrict__ cand_i) {
    __shared__ ushort lists[256][18];    // [tid][0..7]=A ids, [8..15]=B ids, [16]=trash, [17]=pad
    __shared__ ushort outl[256][8];
    int tid = threadIdx.x, blk = blockIdx.x;
    int b  = blk >> 8;                   // 256 blocks per batch (32 ig x 8 sl)
    int ig = (blk >> 3) & 31;
    int sl = blk & 7;
    int wid = tid >> 6, lane = tid & 63;
    int ln31 = lane & 31, l5 = lane >> 5;
    int koff = l5 * 8;
    int i0w = ig * 128 + wid * 32;       // this wave's 32-aligned i-tile base
    int i   = i0w + ln31;
    long bN = (long)b * NN;
    int rbase = l5 * 4;
    int jbase = sl * 512;

    bf16x8 bi_h = *(const bf16x8*)&hHi [(bN + i) * 16 + koff];
    bf16x8 bi_m = *(const bf16x8*)&hMid[(bN + i) * 16 + koff];
    bf16x8 bi_l = *(const bf16x8*)&hLo [(bN + i) * 16 + koff];

    // ---- pass 1: top-8 scores only (sorted descending invariant) ----
    float s[8];
#pragma unroll
    for (int k = 0; k < 8; k++) s[k] = -FLT_MAX;
#pragma unroll 2
    for (int t = 0; t < 16; t++) {
        int j0 = jbase + t * 32;
        float scv[16];
        tile_scores(hHi, hMid, hLo, nsq, bN, j0, ln31, koff, rbase, i0w,
                    bi_h, bi_m, bi_l, scv);
        float va[8] = { scv[0], scv[1], scv[2], scv[3], scv[4], scv[5], scv[6], scv[7] };
        float vb[8] = { scv[8], scv[9], scv[10], scv[11], scv[12], scv[13], scv[14], scv[15] };
        sort8d(va); sort8d(vb);
        float mg[8];
#pragma unroll
        for (int k = 0; k < 8; k++) mg[k] = fmaxf(va[k], vb[7 - k]);  // top-8 of 16, bitonic
        bsort8d(mg);
#pragma unroll
        for (int k = 0; k < 8; k++) s[k] = fmaxf(s[k], mg[7 - k]);    // top-8 of (s ∪ mg), bitonic
        bsort8d(s);
    }
    // pair-merge: top-8 of union(lane, lane^32) as a multiset; theta = its min.
    float mv[8];
#pragma unroll
    for (int k = 0; k < 8; k++) mv[k] = fmaxf(s[k], __shfl_xor(s[7 - k], 32));
    float theta = mv[0];
#pragma unroll
    for (int k = 1; k < 8; k++) theta = fminf(theta, mv[k]);

    // ---- pass 2: id recovery via bitmask + ffs ----
    ushort* ldsw = &lists[0][0];
    int baseA = tid * 18, baseB = baseA + 8, trash = baseA + 16;
    int nA = 0, nB = 0;
#pragma unroll 2
    for (int t = 0; t < 16; t++) {
        int j0 = jbase + t * 32;
        float scv[16];
        tile_scores(hHi, hMid, hLo, nsq, bN, j0, ln31, koff, rbase, i0w,
                    bi_h, bi_m, bi_l, scv);
        unsigned gm = 0, em = 0;
#pragma unroll
        for (int rr = 0; rr < 16; rr++) {
            gm |= (scv[rr] >  theta) ? (1u << rr) : 0u;
            em |= (scv[rr] == theta) ? (1u << rr) : 0u;
        }
        unsigned m = gm | em;
        while (__any(m != 0u)) {
            if (m) {
                int rr = __ffs(m) - 1;
                m &= m - 1u;
                int r = (rr & 3) + ((rr >> 2) << 3) + rbase;
                int j = j0 + r;
                bool isGt = (gm >> rr) & 1u;
                bool cA = isGt && (nA < 8);   // <=7 by math; insurance
                bool cB = (!isGt) && (nB < 8);
                int ia = cA ? (baseA + nA) : (cB ? (baseB + nB) : trash);
                ldsw[ia] = (ushort)j;         // single predicated write
                nA += cA;
                nB += cB;
            }
        }
    }
    int pA = __shfl_xor(nA, 32);
    int pB = __shfl_xor(nB, 32);
    __syncthreads();
    // ---- assembly (per column, lane<32): A ids + smallest-j ties to fill 8 ----
    if (lane < 32) {
        int tp = tid + 32;
        int n = 0;
        for (int k = 0; k < nA && n < 8; k++) outl[tid][n++] = lists[tid][k];
        for (int k = 0; k < pA && n < 8; k++) outl[tid][n++] = lists[tp][k];
        int p0 = 0, p1 = 0;
        while (n < 8) {                  // two-pointer merge of j-ascending tie lists
            unsigned a = (p0 < nB) ? (unsigned)lists[tid][8 + p0] : 0xFFFFFFFFu;
            unsigned c = (p1 < pB) ? (unsigned)lists[tp][8 + p1] : 0xFFFFFFFFu;
            bool t0 = a < c;
            outl[tid][n++] = (ushort)(t0 ? a : c);
            p0 += t0 ? 1 : 0; p1 += t0 ? 0 : 1;
        }
        uint4 pk = *(const uint4*)&outl[tid][0];
        cand_i[(long)(b * NSL + sl) * NN + i] = pk;
    }
}

// --- merge 8 slice-lists + GAT + update-MLP + fire + 1x1->1 + sigmoid -------
// R14: 8 threads/node — lane (ln7, oct): node slot w*8+ln7, slice oct (one
// slice = 8 candidates each, NSL=8). Per-lane exact insertion sort of its 8
// candidates by (score desc, id asc), then 3-level shfl_xor(8/16/32) bitonic
// max-merge with carried ids (validated R9 2-level pattern + one level;
// re-sort after levels 1-2). Gather chain halves (16 -> 8); waves double
// (2048 -> 4096 = 16/CU). MLP: 8 x 16-hd slices + 3-level butterfly (fp32
// reorder class). GAT + epilogue on oct==0 lanes; semantics unchanged.
__launch_bounds__(256)
__global__ void k_gat2(const uint4* __restrict__ cand_i, const float* __restrict__ h,
                       const float* __restrict__ sq,
                       const float* __restrict__ xp, const float* __restrict__ asr,
                       const float* __restrict__ adt, const float* __restrict__ bg,
                       const float* __restrict__ fire, const float* __restrict__ Wu1,
                       const float* __restrict__ bu1, const float* __restrict__ Wu2,
                       const float* __restrict__ bu2, const float* __restrict__ Wo,
                       const float* __restrict__ bo, float* __restrict__ out_low) {
    __shared__ float sU1[128 * 16];
    __shared__ float sU2t[128 * 16];      // [hd][c] = Wu2[c][hd]
    __shared__ float sb1[128];
    __shared__ float pshare[32][17];
    int tid = threadIdx.x;
    int lane = tid & 63, w = tid >> 6;            // 4 waves per block
    for (int k = tid; k < 2048; k += 256) {       // stage MLP weights (amortized 4x)
        sU1[k] = Wu1[k];
        sU2t[(k & 127) * 16 + (k >> 7)] = Wu2[k];
    }
    if (tid < 128) sb1[tid] = bu1[tid];
    int ln7 = lane & 7, oct = lane >> 3;          // oct = slice index 0..7
    int ns = w * 8 + ln7;                         // node slot within block (0..31)
    int t = blockIdx.x * 32 + ns;                 // node 0..32767 (== bN + i)
    int b = t >> 12, i = t & 4095;
    long bN = (long)b * NN;
    const float4* ip = (const float4*)&h[(bN + i) * 16];
    float4 r0 = ip[0], r1 = ip[1], r2 = ip[2], r3 = ip[3];
    float ni[16] = { r0.x,r0.y,r0.z,r0.w, r1.x,r1.y,r1.z,r1.w,
                     r2.x,r2.y,r2.z,r2.w, r3.x,r3.y,r3.z,r3.w };
    float fS[8]; int fI[8];
#pragma unroll
    for (int k = 0; k < 8; k++) { fS[k] = -FLT_MAX; fI[k] = 65535; }
    {
        int sl = oct;                              // one slice per lane
        uint4 pk = cand_i[(long)(b * NSL + sl) * NN + i];
        unsigned idx8[8] = { pk.x & 0xFFFF, pk.x >> 16, pk.y & 0xFFFF, pk.y >> 16,
                             pk.z & 0xFFFF, pk.z >> 16, pk.w & 0xFFFF, pk.w >> 16 };
#pragma unroll
        for (int k = 0; k < 8; k++) {
            int j = (int)idx8[k];
            const float4* np = (const float4*)&h[(bN + j) * 16];
            float4 a0 = np[0], a1 = np[1], a2 = np[2], a3 = np[3];
            float d = dot16m(ni, a0, a1, a2, a3, sq[bN + j]);
            bool bt = (d > fS[7]) || (d == fS[7] && j < fI[7]);
            if (bt) {
                fS[7] = d; fI[7] = j;
#pragma unroll
                for (int qq = 7; qq > 0; qq--) {
                    bool sw = (fS[qq] > fS[qq - 1]) || (fS[qq] == fS[qq - 1] && fI[qq] < fI[qq - 1]);
                    if (sw) {
                        float td = fS[qq]; fS[qq] = fS[qq - 1]; fS[qq - 1] = td;
                        int tj = fI[qq]; fI[qq] = fI[qq - 1]; fI[qq - 1] = tj;
                    }
                }
            }
        }
    }
    // level 1: merge slice pairs (xor 8) — top-8 of 16, re-sort
    float oS[8]; int oI[8];
#pragma unroll
    for (int k = 0; k < 8; k++) {
        oS[k] = __shfl_xor(fS[k], 8);
        oI[k] = __shfl_xor(fI[k], 8);
    }
    float mS[8]; int mI[8];
#pragma unroll
    for (int k = 0; k < 8; k++) {
        bool mine = (fS[k] > oS[7 - k]) || (fS[k] == oS[7 - k] && fI[k] < oI[7 - k]);
        mS[k] = mine ? fS[k] : oS[7 - k];
        mI[k] = mine ? fI[k] : oI[7 - k];
    }
    bsort8d_id(mS, mI);
    // level 2: merge (xor 16) — top-8 of 32, re-sort
#pragma unroll
    for (int k = 0; k < 8; k++) {
        oS[k] = __shfl_xor(mS[k], 16);
        oI[k] = __shfl_xor(mI[k], 16);
    }
#pragma unroll
    for (int k = 0; k < 8; k++) {
        bool mine = (mS[k] > oS[7 - k]) || (mS[k] == oS[7 - k] && mI[k] < oI[7 - k]);
        fS[k] = mine ? mS[k] : oS[7 - k];
        fI[k] = mine ? mI[k] : oI[7 - k];
    }
    bsort8d_id(fS, fI);
    // level 3: merge (xor 32) — top-8 of 64 (final set; no re-sort needed)
#pragma unroll
    for (int k = 0; k < 8; k++) {
        oS[k] = __shfl_xor(fS[k], 32);
        oI[k] = __shfl_xor(fI[k], 32);
    }
    int nI[8];
#pragma unroll
    for (int k = 0; k < 8; k++) {
        bool mine = (fS[k] > oS[7 - k]) || (fS[k] == oS[7 - k] && fI[k] < oI[7 - k]);
        nI[k] = mine ? fI[k] : oI[7 - k];
    }
    if (oct == 0) {
        int nbrs[9];
#pragma unroll
        for (int e = 0; e < 8; e++) nbrs[e] = nI[e];
        nbrs[8] = i;                                   // self-loop
        float adtv[4];
#pragma unroll
        for (int hh = 0; hh < 4; hh++) adtv[hh] = adt[(bN + i) * 4 + hh];
        float mx[4] = { -FLT_MAX, -FLT_MAX, -FLT_MAX, -FLT_MAX };
        float lg[9][4];
#pragma unroll
        for (int e = 0; e < 9; e++) {
            long nb = bN + nbrs[e];
#pragma unroll
            for (int hh = 0; hh < 4; hh++) {
                float l = asr[nb * 4 + hh] + adtv[hh];
                l = (l > 0.f) ? l : 0.2f * l;          // leaky_relu 0.2
                lg[e][hh] = l;
                mx[hh] = fmaxf(mx[hh], l);
            }
        }
        float sum[4] = { 0, 0, 0, 0 };
        float acc[16];
#pragma unroll
        for (int c = 0; c < 16; c++) acc[c] = 0.f;
#pragma unroll
        for (int e = 0; e < 9; e++) {
            long nb = bN + nbrs[e];
            const float4* xpn = (const float4*)&xp[nb * 16];
            float4 x0 = xpn[0], x1 = xpn[1], x2 = xpn[2], x3 = xpn[3];
            float xv[16] = { x0.x,x0.y,x0.z,x0.w, x1.x,x1.y,x1.z,x1.w,
                             x2.x,x2.y,x2.z,x2.w, x3.x,x3.y,x3.z,x3.w };
            float wv[4];
#pragma unroll
            for (int hh = 0; hh < 4; hh++) {
                float w2 = expf(lg[e][hh] - mx[hh]);
                sum[hh] += w2; wv[hh] = w2;
            }
#pragma unroll
            for (int hh = 0; hh < 4; hh++)
#pragma unroll
                for (int f = 0; f < 4; f++)
                    acc[hh * 4 + f] += wv[hh] * xv[hh * 4 + f];
        }
#pragma unroll
        for (int hh = 0; hh < 4; hh++) {
            float inv = 1.f / sum[hh];
#pragma unroll
            for (int f = 0; f < 4; f++) {
                float o = acc[hh * 4 + f] * inv + bg[hh * 4 + f];
                pshare[ns][hh * 4 + f] = fmaxf(o, 0.f);   // GAT relu -> LDS (p dead)
            }
        }
    }
    __syncthreads();
    // ---- fused update-MLP: lane (ns, oct) = node ns, hd slice oct (16 hd)
    float pv[16];
#pragma unroll
    for (int c = 0; c < 16; c++) pv[c] = pshare[ns][c];
    float u[16];
#pragma unroll
    for (int c = 0; c < 16; c++) u[c] = 0.f;
    int hd0 = oct * 16;
    for (int hd = hd0; hd < hd0 + 16; hd++) {        // wave-uniform LDS addrs: broadcast
        const float4* r = (const float4*)&sU1[hd * 16];
        float4 w0 = r[0], w1 = r[1], w2 = r[2], w3 = r[3];
        float a = sb1[hd]
            + w0.x*pv[0] + w0.y*pv[1] + w0.z*pv[2] + w0.w*pv[3]
            + w1.x*pv[4] + w1.y*pv[5] + w1.z*pv[6] + w1.w*pv[7]
            + w2.x*pv[8] + w2.y*pv[9] + w2.z*pv[10]+ w2.w*pv[11]
            + w3.x*pv[12]+ w3.y*pv[13]+ w3.z*pv[14]+ w3.w*pv[15];
        a = fmaxf(a, 0.f);
        const float4* tt = (const float4*)&sU2t[hd * 16];
        float4 t0 = tt[0], t1 = tt[1], t2 = tt[2], t3 = tt[3];
        u[0] += t0.x*a; u[1] += t0.y*a; u[2] += t0.z*a; u[3] += t0.w*a;
        u[4] += t1.x*a; u[5] += t1.y*a; u[6] += t1.z*a; u[7] += t1.w*a;
        u[8] += t2.x*a; u[9] += t2.y*a; u[10]+= t2.z*a; u[11]+= t2.w*a;
        u[12]+= t3.x*a; u[13]+= t3.y*a; u[14]+= t3.z*a; u[15]+= t3.w*a;
    }
    // butterfly-reduce the 8 slice-partials (fp32 reorder class)
#pragma unroll
    for (int c = 0; c < 16; c++) {
        u[c] += __shfl_xor(u[c], 8);
        u[c] += __shfl_xor(u[c], 16);
        u[c] += __shfl_xor(u[c], 32);
    }
    if (oct == 0) {
        float mask = (fire[t] < 0.5f) ? 1.f : 0.f;
        float o = bo[0];
#pragma unroll
        for (int c = 0; c < 16; c++)
            o += Wo[c] * (ni[c] + mask * (u[c] + bu2[c]));   // ni == h[t]
        out_low[t] = 1.f / (1.f + expf(-o));
    }
}

// ---------------- bilinear upsample 64 -> 256 (half-pixel, clamp) -----------
// (validated R13; unchanged)
__launch_bounds__(256)
__global__ void k_up(const float* __restrict__ ol, float* __restrict__ out) {
    int idx = blockIdx.x * 256 + threadIdx.x;      // 0..131071 (4 pixels each)
    int b = idx >> 14, rem = idx & 16383;
    int oy = rem >> 6, ox0 = (rem & 63) * 4;
    float cy = (oy + 0.5f) * 0.25f - 0.5f;
    int iy0 = (int)floorf(cy); float fy = cy - (float)iy0;
    int y0 = min(max(iy0, 0), 63), y1 = min(max(iy0 + 1, 0), 63);
    const float* s = ol + b * NN;
    float res[4];
#pragma unroll
    for (int e = 0; e < 4; e++) {
        int ox = ox0 + e;
        float cx = (ox + 0.5f) * 0.25f - 0.5f;
        int ix0 = (int)floorf(cx); float fx = cx - (float)ix0;
        int x0 = min(max(ix0, 0), 63), x1 = min(max(ix0 + 1, 0), 63);
        res[e] = (1.f - fy) * ((1.f - fx) * s[y0 * 64 + x0] + fx * s[y0 * 64 + x1])
               + fy * ((1.f - fx) * s[y1 * 64 + x0] + fx * s[y1 * 64 + x1]);
    }
    *(float4*)&out[(long)idx * 4] = make_float4(res[0], res[1], res[2], res[3]);
}

extern "C" void kernel_launch(void* const* d_in, const int* in_sizes, int n_in,
                              void* d_out, int out_size, void* d_ws, size_t ws_size,
                              hipStream_t stream) {
    const float* x    = (const float*)d_in[0];
    const float* fire = (const float*)d_in[1];
    const float* W1   = (const float*)d_in[2];
    const float* b1   = (const float*)d_in[3];
    const float* g1   = (const float*)d_in[4];
    const float* be1  = (const float*)d_in[5];
    const float* m1   = (const float*)d_in[6];
    const float* v1   = (const float*)d_in[7];
    const float* W2   = (const float*)d_in[8];
    const float* b2   = (const float*)d_in[9];
    const float* g2   = (const float*)d_in[10];
    const float* be2  = (const float*)d_in[11];
    const float* m2   = (const float*)d_in[12];
    const float* v2   = (const float*)d_in[13];
    const float* Wg   = (const float*)d_in[14];
    const float* a_src= (const float*)d_in[15];
    const float* a_dst= (const float*)d_in[16];
    const float* bg   = (const float*)d_in[17];
    const float* Wu1  = (const float*)d_in[18];
    const float* bu1  = (const float*)d_in[19];
    const float* Wu2  = (const float*)d_in[20];
    const float* bu2  = (const float*)d_in[21];
    const float* Wo   = (const float*)d_in[22];
    const float* bo   = (const float*)d_in[23];

    float* ws  = (float*)d_ws;
    float* h1  = ws + OFF_H1;
    float* h   = ws + OFF_H;
    float* sq  = ws + OFF_SQ;
    float* xp  = ws + OFF_XP;
    float* asr = ws + OFF_ASR;
    float* adt = ws + OFF_ADT;
    float* ol  = ws + OFF_OL;
    // H1 region reuse (dead after conv2): cand_i 4 MB (NSL=8), bf16 splits,
    // nsq. Total 1,867,776 of 2,097,152 floats — no footprint growth.
    uint4*  cand_i = (uint4*)(ws + OFF_H1);
    ushort* hHi    = (ushort*)(ws + OFF_H1 + 1048576);
    ushort* hMid   = (ushort*)(ws + OFF_H1 + 1310720);
    ushort* hLo    = (ushort*)(ws + OFF_H1 + 1572864);
    float*  nsq    = ws + OFF_H1 + 1835008;

    k_dconv1<<<BATCH * 32, 512, 0, stream>>>(x, W1, b1, g1, be1, m1, v1, h1);
    k_conv2 <<<BATCH * 32, 512, 0, stream>>>(h1, W2, b2, g2, be2, m2, v2, Wg, a_src, a_dst,
                                             h, sq, xp, asr, adt);
    k_split <<<BATCH * NN / 256, 256, 0, stream>>>(h, sq, hHi, hMid, hLo, nsq);
    k_scan  <<<BATCH * 32 * NSL, 256, 0, stream>>>(hHi, hMid, hLo, nsq, cand_i);
    k_gat2  <<<BATCH * NN / 32, 256, 0, stream>>>(cand_i, h, sq, xp, asr, adt, bg,
                                                  fire, Wu1, bu1, Wu2, bu2, Wo, bo, ol);
    k_up    <<<(BATCH * HIGH * HIGH / 4) / 256, 256, 0, stream>>>(ol, (float*)d_out);
}

// Round 15
// 266.679 us; speedup vs baseline: 1.0216x; 1.0216x over previous
//
#include <hip/hip_runtime.h>
#include <math.h>
#include <float.h>

#define BATCH 8
#define HIGH  256
#define LOWR  64
#define NN    4096          // LOWR*LOWR
#define HIDC  16
#define C1    64
#define NSL   8             // j-slices in kNN scan (512 j each)

// workspace layout (floats) — footprint identical to the validated layout
#define OFF_XL   0                               // DEAD (down fused into conv1)
#define OFF_H1   (OFF_XL  + BATCH*NN)            // 2.097M floats; reused after conv2:
                                                 //   [0 .. 1,048,575]         cand_i (4 MB, NSL=8)
                                                 //   [1,048,576 .. 1,835,007] bf16 hi/mid/lo splits
                                                 //   [1,835,008 .. 1,867,775] nsq (= -sq)
#define OFF_H    (OFF_H1  + BATCH*C1*NN)         // node-major [B*N][16]
#define OFF_SQ   (OFF_H   + BATCH*NN*HIDC)       // 0.5*|h|^2 per node
#define OFF_XP   (OFF_SQ  + BATCH*NN)
#define OFF_ASR  (OFF_XP  + BATCH*NN*HIDC)
#define OFF_ADT  (OFF_ASR + BATCH*NN*4)
#define OFF_P    (OFF_ADT + BATCH*NN*4)          // DEAD (update fused into gat2, R10)
#define OFF_OL   (OFF_P   + BATCH*NN*HIDC)

typedef __attribute__((ext_vector_type(8)))  short bf16x8;
typedef __attribute__((ext_vector_type(16))) float f32x16;

// identical-arithmetic dot used by k_gat2 (exact fp32 re-score of the pool —
// final selection semantics unchanged from the validated kernel)
__device__ __forceinline__ float dot16m(const float ni[16], float4 a0, float4 a1,
                                        float4 a2, float4 a3, float hs) {
    return ni[0]*a0.x + ni[1]*a0.y + ni[2]*a0.z + ni[3]*a0.w
         + ni[4]*a1.x + ni[5]*a1.y + ni[6]*a1.z + ni[7]*a1.w
         + ni[8]*a2.x + ni[9]*a2.y + ni[10]*a2.z + ni[11]*a2.w
         + ni[12]*a3.x + ni[13]*a3.y + ni[14]*a3.z + ni[15]*a3.w
         - hs;
}

// ---- fused: bilinear downsample 256->64 (tile+halo in LDS) + conv3x3 1->64 --
// (validated R12; unchanged)
__launch_bounds__(512)
__global__ void k_dconv1(const float* __restrict__ x, const float* __restrict__ W1,
                         const float* __restrict__ b1, const float* __restrict__ g1,
                         const float* __restrict__ be1, const float* __restrict__ m1,
                         const float* __restrict__ v1, float* __restrict__ h1) {
    __shared__ float sW[576];
    __shared__ float sb[64], sg[64], sbe[64], sm[64], sv[64];
    __shared__ float sxl[4][66];
    int tid = threadIdx.x;
    for (int k = tid; k < 576; k += 512) sW[k] = W1[k];
    if (tid < 64) {
        sb[tid] = b1[tid]; sg[tid] = g1[tid]; sbe[tid] = be1[tid];
        sm[tid] = m1[tid]; sv[tid] = v1[tid];
    }
    int blk = blockIdx.x;                 // 8 batches * 32 y-tiles
    int b = blk >> 5, ytile = blk & 31;
    if (tid < 264) {                      // 4 rows x 66 cols (incl. halo)
        int tr = tid / 66, tc = tid - tr * 66;
        int oy = ytile * 2 - 1 + tr, ox = tc - 1;
        float val = 0.f;
        if (oy >= 0 && oy < 64 && ox >= 0 && ox < 64) {
            const float* xb = x + b * HIGH * HIGH;
            float cy = 4.f * oy + 1.5f, cx = 4.f * ox + 1.5f;
            float wy[8], wx[8], sy = 0.f, sx = 0.f;
#pragma unroll
            for (int k = 0; k < 8; k++) {
                int iy = 4 * oy - 2 + k;
                float w = 1.f - fabsf((float)iy - cy) * 0.25f;
                if (iy < 0 || iy >= HIGH) w = 0.f;
                wy[k] = w; sy += w;
                int ix = 4 * ox - 2 + k;
                float v = 1.f - fabsf((float)ix - cx) * 0.25f;
                if (ix < 0 || ix >= HIGH) v = 0.f;
                wx[k] = v; sx += v;
            }
            float acc = 0.f;
#pragma unroll
            for (int ky = 0; ky < 8; ky++) {
                if (wy[ky] == 0.f) continue;
                int iy = 4 * oy - 2 + ky;
                float rowacc = 0.f;
#pragma unroll
                for (int kx = 0; kx < 8; kx++) {
                    if (wx[kx] == 0.f) continue;
                    int ix = 4 * ox - 2 + kx;
                    rowacc += wx[kx] * xb[iy * HIGH + ix];
                }
                acc += wy[ky] * rowacc;
            }
            val = acc / (sy * sx);
        }
        sxl[tr][tc] = val;
    }
    __syncthreads();
    int pix = tid & 127, row = pix >> 6, col = pix & 63;
    float t00 = sxl[row    ][col], t01 = sxl[row    ][col + 1], t02 = sxl[row    ][col + 2];
    float t10 = sxl[row + 1][col], t11 = sxl[row + 1][col + 1], t12 = sxl[row + 1][col + 2];
    float t20 = sxl[row + 2][col], t21 = sxl[row + 2][col + 1], t22 = sxl[row + 2][col + 2];
    int y = ytile * 2 + row;
    long base = (long)b * C1 * NN + (long)y * 64 + col;
#pragma unroll
    for (int it = 0; it < 16; it++) {
        int co = it * 4 + (tid >> 7);     // wave-uniform
        const float* w = &sW[co * 9];
        float acc = 0.f;                  // tap order identical to unfused conv1
        acc += w[0] * t00; acc += w[1] * t01; acc += w[2] * t02;
        acc += w[3] * t10; acc += w[4] * t11; acc += w[5] * t12;
        acc += w[6] * t20; acc += w[7] * t21; acc += w[8] * t22;
        acc += sb[co];
        float sc = sg[co] / sqrtf(sv[co] + 1e-5f);
        acc = (acc - sm[co]) * sc + sbe[co];
        h1[base + (long)co * NN] = fmaxf(acc, 0.f);
    }
}

// ------- conv3x3 64->16 + BN + relu, fused: h (node-major), sq, xp, asr, adt -
// (validated R7; unchanged)
__launch_bounds__(512)
__global__ void k_conv2(const float* __restrict__ h1, const float* __restrict__ W2,
                        const float* __restrict__ b2, const float* __restrict__ g2,
                        const float* __restrict__ be2, const float* __restrict__ m2,
                        const float* __restrict__ v2, const float* __restrict__ Wg,
                        const float* __restrict__ a_src, const float* __restrict__ a_dst,
                        float* __restrict__ h, float* __restrict__ sq,
                        float* __restrict__ xp, float* __restrict__ asr,
                        float* __restrict__ adt) {
    __shared__ float sW2t[576 * 16];    // [ci*9+tap][o]
    __shared__ float sWg[256];
    __shared__ float sA[32];
    __shared__ float accH[3][128][17];  // partials from quarters 1..3 (17-pad)
    int tid = threadIdx.x;
    for (int k = tid; k < 9216; k += 512) {          // coalesced global read, scatter to LDS
        int o = k / 576, ct = k - o * 576;
        sW2t[ct * 16 + o] = W2[k];
    }
    if (tid < 256) sWg[tid] = Wg[tid];
    if (tid < 16) { sA[tid] = a_src[tid]; sA[16 + tid] = a_dst[tid]; }
    __syncthreads();
    int blk = blockIdx.x;                 // 8 batches * 32 y-tiles
    int b = blk >> 5, ytile = blk & 31;
    int q = tid >> 7;                     // ci quarter 0..3
    int sub = tid & 127;
    int ty = sub >> 6, x = sub & 63, y = ytile * 2 + ty;
    float acc[16];
#pragma unroll
    for (int o = 0; o < 16; o++) acc[o] = 0.f;
    const float* hb = h1 + (long)b * C1 * NN + (long)q * 16 * NN;
    for (int ci = 0; ci < 16; ci++) {
        const float* plane = hb + ci * NN;
#pragma unroll
        for (int dy = -1; dy <= 1; dy++) {
            int yy = y + dy; bool oky = (yy >= 0 && yy < 64);
#pragma unroll
            for (int dx = -1; dx <= 1; dx++) {
                int xx = x + dx;
                float v = (oky && xx >= 0 && xx < 64) ? plane[yy * 64 + xx] : 0.f;
                int ct = (q * 16 + ci) * 9 + (dy + 1) * 3 + (dx + 1);
                const float4* wr = (const float4*)&sW2t[ct * 16];
                float4 w0 = wr[0], w1 = wr[1], w2 = wr[2], w3 = wr[3];
                acc[0] += v * w0.x; acc[1] += v * w0.y; acc[2] += v * w0.z; acc[3] += v * w0.w;
                acc[4] += v * w1.x; acc[5] += v * w1.y; acc[6] += v * w1.z; acc[7] += v * w1.w;
                acc[8] += v * w2.x; acc[9] += v * w2.y; acc[10]+= v * w2.z; acc[11]+= v * w2.w;
                acc[12]+= v * w3.x; acc[13]+= v * w3.y; acc[14]+= v * w3.z; acc[15]+= v * w3.w;
            }
        }
    }
    if (q != 0) {
        float* dst = &accH[q - 1][sub][0];
#pragma unroll
        for (int o = 0; o < 16; o++) dst[o] = acc[o];
    }
    __syncthreads();
    if (q != 0) return;
#pragma unroll
    for (int qq = 0; qq < 3; qq++) {
        const float* src = &accH[qq][sub][0];
#pragma unroll
        for (int o = 0; o < 16; o++) acc[o] += src[o];
    }
    int n = y * 64 + x;
    long node = (long)b * NN + n;
    float nodev[16], sqv = 0.f;
#pragma unroll
    for (int o = 0; o < 16; o++) {
        float a = acc[o] + b2[o];
        float sc = g2[o] / sqrtf(v2[o] + 1e-5f);
        a = (a - m2[o]) * sc + be2[o];
        a = fmaxf(a, 0.f);
        nodev[o] = a; sqv += a * a;
        h[node * 16 + o] = a;
    }
    sq[node] = 0.5f * sqv;                // pre-scaled: scan/merge use dot - 0.5|j|^2
    float xpv[16];
#pragma unroll
    for (int o = 0; o < 16; o++) {
        float a = 0.f;
#pragma unroll
        for (int c = 0; c < 16; c++) a += sWg[o * 16 + c] * nodev[c];
        xpv[o] = a;
        xp[node * 16 + o] = a;
    }
#pragma unroll
    for (int hh = 0; hh < 4; hh++) {
        float as = 0.f, ad = 0.f;
#pragma unroll
        for (int f = 0; f < 4; f++) {
            as += xpv[hh * 4 + f] * sA[hh * 4 + f];
            ad += xpv[hh * 4 + f] * sA[16 + hh * 4 + f];
        }
        asr[node * 4 + hh] = as;
        adt[node * 4 + hh] = ad;
    }
}

// ------- error-free 3-way bf16 split of h: h = hi + mid + lo + O(2^-27) -----
__device__ __forceinline__ ushort f2bf(float f) {
    unsigned u = __float_as_uint(f);
    return (ushort)((u + 0x7FFFu + ((u >> 16) & 1u)) >> 16);
}
__device__ __forceinline__ float bf2f(ushort h) {
    return __uint_as_float(((unsigned)h) << 16);
}
__launch_bounds__(256)
__global__ void k_split(const float* __restrict__ h, const float* __restrict__ sq,
                        ushort* __restrict__ hHi, ushort* __restrict__ hMid,
                        ushort* __restrict__ hLo, float* __restrict__ nsq) {
    long t = (long)blockIdx.x * 256 + threadIdx.x;   // node 0..32767
    nsq[t] = -sq[t];                                  // negated for MFMA C-init
    const float4* hp = (const float4*)&h[t * 16];
    float4 v0 = hp[0], v1 = hp[1], v2 = hp[2], v3 = hp[3];
    float v[16] = { v0.x,v0.y,v0.z,v0.w, v1.x,v1.y,v1.z,v1.w,
                    v2.x,v2.y,v2.z,v2.w, v3.x,v3.y,v3.z,v3.w };
    unsigned wh[8], wm[8], wl[8];
#pragma unroll
    for (int p = 0; p < 8; p++) {
        unsigned packh = 0, packm = 0, packl = 0;
#pragma unroll
        for (int e = 0; e < 2; e++) {
            float f = v[p * 2 + e];
            ushort hi = f2bf(f);
            float t1 = f - bf2f(hi);
            ushort mi = f2bf(t1);
            float t2 = t1 - bf2f(mi);
            ushort lo = f2bf(t2);
            packh |= ((unsigned)hi) << (16 * e);
            packm |= ((unsigned)mi) << (16 * e);
            packl |= ((unsigned)lo) << (16 * e);
        }
        wh[p] = packh; wm[p] = packm; wl[p] = packl;
    }
    uint4* dh = (uint4*)&hHi[t * 16];
    uint4* dm = (uint4*)&hMid[t * 16];
    uint4* dl = (uint4*)&hLo[t * 16];
    dh[0] = make_uint4(wh[0], wh[1], wh[2], wh[3]);
    dh[1] = make_uint4(wh[4], wh[5], wh[6], wh[7]);
    dm[0] = make_uint4(wm[0], wm[1], wm[2], wm[3]);
    dm[1] = make_uint4(wm[4], wm[5], wm[6], wm[7]);
    dl[0] = make_uint4(wl[0], wl[1], wl[2], wl[3]);
    dl[1] = make_uint4(wl[4], wl[5], wl[6], wl[7]);
}

// --- shared tile-score routine: MUST be bit-identical between pass 1/2 ------
__device__ __forceinline__ void tile_scores(const ushort* __restrict__ hHi,
        const ushort* __restrict__ hMid, const ushort* __restrict__ hLo,
        const float* __restrict__ nsq, long bN, int j0, int ln31, int koff,
        int rbase, int i0w, bf16x8 bi_h, bf16x8 bi_m, bf16x8 bi_l,
        float scv[16]) {
    int jr = j0 + ln31;
    bf16x8 aj_h = *(const bf16x8*)&hHi [(bN + jr) * 16 + koff];
    bf16x8 aj_m = *(const bf16x8*)&hMid[(bN + jr) * 16 + koff];
    bf16x8 aj_l = *(const bf16x8*)&hLo [(bN + jr) * 16 + koff];
    float4 q0 = *(const float4*)&nsq[bN + j0 +  0 + rbase];
    float4 q1 = *(const float4*)&nsq[bN + j0 +  8 + rbase];
    float4 q2 = *(const float4*)&nsq[bN + j0 + 16 + rbase];
    float4 q3 = *(const float4*)&nsq[bN + j0 + 24 + rbase];
    f32x16 acc;
    acc[0]  = q0.x; acc[1]  = q0.y; acc[2]  = q0.z; acc[3]  = q0.w;
    acc[4]  = q1.x; acc[5]  = q1.y; acc[6]  = q1.z; acc[7]  = q1.w;
    acc[8]  = q2.x; acc[9]  = q2.y; acc[10] = q2.z; acc[11] = q2.w;
    acc[12] = q3.x; acc[13] = q3.y; acc[14] = q3.z; acc[15] = q3.w;
    acc = __builtin_amdgcn_mfma_f32_32x32x16_bf16(aj_h, bi_h, acc, 0, 0, 0);
    acc = __builtin_amdgcn_mfma_f32_32x32x16_bf16(aj_h, bi_m, acc, 0, 0, 0);
    acc = __builtin_amdgcn_mfma_f32_32x32x16_bf16(aj_m, bi_h, acc, 0, 0, 0);
    acc = __builtin_amdgcn_mfma_f32_32x32x16_bf16(aj_h, bi_l, acc, 0, 0, 0);
    acc = __builtin_amdgcn_mfma_f32_32x32x16_bf16(aj_l, bi_h, acc, 0, 0, 0);
    acc = __builtin_amdgcn_mfma_f32_32x32x16_bf16(aj_m, bi_m, acc, 0, 0, 0);
#pragma unroll
    for (int rr = 0; rr < 16; rr++) scv[rr] = acc[rr];
    if (j0 == i0w) {                       // wave-uniform: diagonal tile, mask self
#pragma unroll
        for (int rr = 0; rr < 16; rr++) {
            int r = (rr & 3) + 8 * (rr >> 2) + rbase;
            if (r == ln31) scv[rr] = -FLT_MAX;
        }
    }
}

// --- sorting-network primitives (compare-exchange = max/min pair: exact
// multiset preservation, fully unrolled constant indexing) ------------------
#define CEX(a, b) { float ce_hi = fmaxf(a, b), ce_lo = fminf(a, b); (a) = ce_hi; (b) = ce_lo; }
// Batcher odd-even mergesort, 8 values descending (19 CE)
__device__ __forceinline__ void sort8d(float v[8]) {
    CEX(v[0],v[1]); CEX(v[2],v[3]); CEX(v[4],v[5]); CEX(v[6],v[7]);
    CEX(v[0],v[2]); CEX(v[1],v[3]); CEX(v[4],v[6]); CEX(v[5],v[7]);
    CEX(v[1],v[2]); CEX(v[5],v[6]);
    CEX(v[0],v[4]); CEX(v[1],v[5]); CEX(v[2],v[6]); CEX(v[3],v[7]);
    CEX(v[2],v[4]); CEX(v[3],v[5]);
    CEX(v[1],v[2]); CEX(v[3],v[4]); CEX(v[5],v[6]);
}
// bitonic 8-sequence -> sorted descending (12 CE)
__device__ __forceinline__ void bsort8d(float v[8]) {
    CEX(v[0],v[4]); CEX(v[1],v[5]); CEX(v[2],v[6]); CEX(v[3],v[7]);
    CEX(v[0],v[2]); CEX(v[1],v[3]); CEX(v[4],v[6]); CEX(v[5],v[7]);
    CEX(v[0],v[1]); CEX(v[2],v[3]); CEX(v[4],v[5]); CEX(v[6],v[7]);
}
// compare-exchange with carried id under (score desc, id asc) total order
#define CEX2(sa, ia, sb, ib) { \
    bool sw2 = ((sb) > (sa)) || ((sb) == (sa) && (ib) < (ia)); \
    float th2 = sw2 ? (sb) : (sa); float tl2 = sw2 ? (sa) : (sb); \
    int   ih2 = sw2 ? (ib) : (ia); int   il2 = sw2 ? (ia) : (ib); \
    (sa) = th2; (sb) = tl2; (ia) = ih2; (ib) = il2; }
// bitonic 8 -> sorted by (score desc, id asc), ids carried (12 CE2)
__device__ __forceinline__ void bsort8d_id(float v[8], int id[8]) {
    CEX2(v[0],id[0],v[4],id[4]); CEX2(v[1],id[1],v[5],id[5]);
    CEX2(v[2],id[2],v[6],id[6]); CEX2(v[3],id[3],v[7],id[7]);
    CEX2(v[0],id[0],v[2],id[2]); CEX2(v[1],id[1],v[3],id[3]);
    CEX2(v[4],id[4],v[6],id[6]); CEX2(v[5],id[5],v[7],id[7]);
    CEX2(v[0],id[0],v[1],id[1]); CEX2(v[2],id[2],v[3],id[3]);
    CEX2(v[4],id[4],v[5],id[5]); CEX2(v[6],id[6],v[7],id[7]);
}

// --------- kNN scan, two-pass scores-only selection (validated R6-R9) --------
// At structural floor per R9 falsifier: ~89% pipe-busy, selection networks at
// the CE lower bound, occupancy lever exhausted.
__global__ __attribute__((amdgpu_waves_per_eu(4, 8))) __launch_bounds__(256)
void k_scan(const ushort* __restrict__ hHi, const ushort* __restrict__ hMid,
            const ushort* __restrict__ hLo, const float* __restrict__ nsq,
            uint4* __restrict__ cand_i) {
    __shared__ ushort lists[256][18];    // [tid][0..7]=A ids, [8..15]=B ids, [16]=trash, [17]=pad
    __shared__ ushort outl[256][8];
    int tid = threadIdx.x, blk = blockIdx.x;
    int b  = blk >> 8;                   // 256 blocks per batch (32 ig x 8 sl)
    int ig = (blk >> 3) & 31;
    int sl = blk & 7;
    int wid = tid >> 6, lane = tid & 63;
    int ln31 = lane & 31, l5 = lane >> 5;
    int koff = l5 * 8;
    int i0w = ig * 128 + wid * 32;       // this wave's 32-aligned i-tile base
    int i   = i0w + ln31;
    long bN = (long)b * NN;
    int rbase = l5 * 4;
    int jbase = sl * 512;

    bf16x8 bi_h = *(const bf16x8*)&hHi [(bN + i) * 16 + koff];
    bf16x8 bi_m = *(const bf16x8*)&hMid[(bN + i) * 16 + koff];
    bf16x8 bi_l = *(const bf16x8*)&hLo [(bN + i) * 16 + koff];

    // ---- pass 1: top-8 scores only (sorted descending invariant) ----
    float s[8];
#pragma unroll
    for (int k = 0; k < 8; k++) s[k] = -FLT_MAX;
#pragma unroll 2
    for (int t = 0; t < 16; t++) {
        int j0 = jbase + t * 32;
        float scv[16];
        tile_scores(hHi, hMid, hLo, nsq, bN, j0, ln31, koff, rbase, i0w,
                    bi_h, bi_m, bi_l, scv);
        float va[8] = { scv[0], scv[1], scv[2], scv[3], scv[4], scv[5], scv[6], scv[7] };
        float vb[8] = { scv[8], scv[9], scv[10], scv[11], scv[12], scv[13], scv[14], scv[15] };
        sort8d(va); sort8d(vb);
        float mg[8];
#pragma unroll
        for (int k = 0; k < 8; k++) mg[k] = fmaxf(va[k], vb[7 - k]);  // top-8 of 16, bitonic
        bsort8d(mg);
#pragma unroll
        for (int k = 0; k < 8; k++) s[k] = fmaxf(s[k], mg[7 - k]);    // top-8 of (s ∪ mg), bitonic
        bsort8d(s);
    }
    // pair-merge: top-8 of union(lane, lane^32) as a multiset; theta = its min.
    float mv[8];
#pragma unroll
    for (int k = 0; k < 8; k++) mv[k] = fmaxf(s[k], __shfl_xor(s[7 - k], 32));
    float theta = mv[0];
#pragma unroll
    for (int k = 1; k < 8; k++) theta = fminf(theta, mv[k]);

    // ---- pass 2: id recovery via bitmask + ffs ----
    ushort* ldsw = &lists[0][0];
    int baseA = tid * 18, baseB = baseA + 8, trash = baseA + 16;
    int nA = 0, nB = 0;
#pragma unroll 2
    for (int t = 0; t < 16; t++) {
        int j0 = jbase + t * 32;
        float scv[16];
        tile_scores(hHi, hMid, hLo, nsq, bN, j0, ln31, koff, rbase, i0w,
                    bi_h, bi_m, bi_l, scv);
        unsigned gm = 0, em = 0;
#pragma unroll
        for (int rr = 0; rr < 16; rr++) {
            gm |= (scv[rr] >  theta) ? (1u << rr) : 0u;
            em |= (scv[rr] == theta) ? (1u << rr) : 0u;
        }
        unsigned m = gm | em;
        while (__any(m != 0u)) {
            if (m) {
                int rr = __ffs(m) - 1;
                m &= m - 1u;
                int r = (rr & 3) + ((rr >> 2) << 3) + rbase;
                int j = j0 + r;
                bool isGt = (gm >> rr) & 1u;
                bool cA = isGt && (nA < 8);   // <=7 by math; insurance
                bool cB = (!isGt) && (nB < 8);
                int ia = cA ? (baseA + nA) : (cB ? (baseB + nB) : trash);
                ldsw[ia] = (ushort)j;         // single predicated write
                nA += cA;
                nB += cB;
            }
        }
    }
    int pA = __shfl_xor(nA, 32);
    int pB = __shfl_xor(nB, 32);
    __syncthreads();
    // ---- assembly (per column, lane<32): A ids + smallest-j ties to fill 8 ----
    if (lane < 32) {
        int tp = tid + 32;
        int n = 0;
        for (int k = 0; k < nA && n < 8; k++) outl[tid][n++] = lists[tid][k];
        for (int k = 0; k < pA && n < 8; k++) outl[tid][n++] = lists[tp][k];
        int p0 = 0, p1 = 0;
        while (n < 8) {                  // two-pointer merge of j-ascending tie lists
            unsigned a = (p0 < nB) ? (unsigned)lists[tid][8 + p0] : 0xFFFFFFFFu;
            unsigned c = (p1 < pB) ? (unsigned)lists[tp][8 + p1] : 0xFFFFFFFFu;
            bool t0 = a < c;
            outl[tid][n++] = (ushort)(t0 ? a : c);
            p0 += t0 ? 1 : 0; p1 += t0 ? 0 : 1;
        }
        uint4 pk = *(const uint4*)&outl[tid][0];
        cand_i[(long)(b * NSL + sl) * NN + i] = pk;
    }
}

// --- merge 8 slice-lists + GAT + update-MLP + fire + 1x1->1 + sigmoid -------
// (validated R13: 256-thread blocks, 4 waves x 16 nodes, 4 threads/node;
// R14's 8-threads/node split regressed — reverted)
__launch_bounds__(256)
__global__ void k_gat2(const uint4* __restrict__ cand_i, const float* __restrict__ h,
                       const float* __restrict__ sq,
                       const float* __restrict__ xp, const float* __restrict__ asr,
                       const float* __restrict__ adt, const float* __restrict__ bg,
                       const float* __restrict__ fire, const float* __restrict__ Wu1,
                       const float* __restrict__ bu1, const float* __restrict__ Wu2,
                       const float* __restrict__ bu2, const float* __restrict__ Wo,
                       const float* __restrict__ bo, float* __restrict__ out_low) {
    __shared__ float sU1[128 * 16];
    __shared__ float sU2t[128 * 16];      // [hd][c] = Wu2[c][hd]
    __shared__ float sb1[128];
    __shared__ float pshare[64][17];
    int tid = threadIdx.x;
    int lane = tid & 63, w = tid >> 6;            // 4 waves per block
    for (int k = tid; k < 2048; k += 256) {       // stage MLP weights (amortized 4x)
        sU1[k] = Wu1[k];
        sU2t[(k & 127) * 16 + (k >> 7)] = Wu2[k];
    }
    if (tid < 128) sb1[tid] = bu1[tid];
    int ln15 = lane & 15, q = lane >> 4;
    int ns = w * 16 + ln15;                       // node slot within block (0..63)
    int t = blockIdx.x * 64 + ns;                 // node 0..32767 (== bN + i)
    int b = t >> 12, i = t & 4095;
    long bN = (long)b * NN;
    const float4* ip = (const float4*)&h[(bN + i) * 16];
    float4 r0 = ip[0], r1 = ip[1], r2 = ip[2], r3 = ip[3];
    float ni[16] = { r0.x,r0.y,r0.z,r0.w, r1.x,r1.y,r1.z,r1.w,
                     r2.x,r2.y,r2.z,r2.w, r3.x,r3.y,r3.z,r3.w };
    float fS[8]; int fI[8];
#pragma unroll
    for (int k = 0; k < 8; k++) { fS[k] = -FLT_MAX; fI[k] = 65535; }
#pragma unroll
    for (int ss = 0; ss < 2; ss++) {
        int sl = q * 2 + ss;
        uint4 pk = cand_i[(long)(b * NSL + sl) * NN + i];
        unsigned idx8[8] = { pk.x & 0xFFFF, pk.x >> 16, pk.y & 0xFFFF, pk.y >> 16,
                             pk.z & 0xFFFF, pk.z >> 16, pk.w & 0xFFFF, pk.w >> 16 };
#pragma unroll
        for (int k = 0; k < 8; k++) {
            int j = (int)idx8[k];
            const float4* np = (const float4*)&h[(bN + j) * 16];
            float4 a0 = np[0], a1 = np[1], a2 = np[2], a3 = np[3];
            float d = dot16m(ni, a0, a1, a2, a3, sq[bN + j]);
            bool bt = (d > fS[7]) || (d == fS[7] && j < fI[7]);
            if (bt) {
                fS[7] = d; fI[7] = j;
#pragma unroll
                for (int qq = 7; qq > 0; qq--) {
                    bool sw = (fS[qq] > fS[qq - 1]) || (fS[qq] == fS[qq - 1] && fI[qq] < fI[qq - 1]);
                    if (sw) {
                        float td = fS[qq]; fS[qq] = fS[qq - 1]; fS[qq - 1] = td;
                        int tj = fI[qq]; fI[qq] = fI[qq - 1]; fI[qq - 1] = tj;
                    }
                }
            }
        }
    }
    // level 1: merge quarter pairs (0<->1, 2<->3) — top-8 of 32, then re-sort
    float oS[8]; int oI[8];
#pragma unroll
    for (int k = 0; k < 8; k++) {
        oS[k] = __shfl_xor(fS[k], 16);
        oI[k] = __shfl_xor(fI[k], 16);
    }
    float mS[8]; int mI[8];
#pragma unroll
    for (int k = 0; k < 8; k++) {
        bool mine = (fS[k] > oS[7 - k]) || (fS[k] == oS[7 - k] && fI[k] < oI[7 - k]);
        mS[k] = mine ? fS[k] : oS[7 - k];
        mI[k] = mine ? fI[k] : oI[7 - k];
    }
    bsort8d_id(mS, mI);
    // level 2: merge across (01)<->(23) — top-8 of 64
#pragma unroll
    for (int k = 0; k < 8; k++) {
        oS[k] = __shfl_xor(mS[k], 32);
        oI[k] = __shfl_xor(mI[k], 32);
    }
    int nI[8];
#pragma unroll
    for (int k = 0; k < 8; k++) {
        bool mine = (mS[k] > oS[7 - k]) || (mS[k] == oS[7 - k] && mI[k] < oI[7 - k]);
        nI[k] = mine ? mI[k] : oI[7 - k];
    }
    if (q == 0) {
        int nbrs[9];
#pragma unroll
        for (int e = 0; e < 8; e++) nbrs[e] = nI[e];
        nbrs[8] = i;                                   // self-loop
        float adtv[4];
#pragma unroll
        for (int hh = 0; hh < 4; hh++) adtv[hh] = adt[(bN + i) * 4 + hh];
        float mx[4] = { -FLT_MAX, -FLT_MAX, -FLT_MAX, -FLT_MAX };
        float lg[9][4];
#pragma unroll
        for (int e = 0; e < 9; e++) {
            long nb = bN + nbrs[e];
#pragma unroll
            for (int hh = 0; hh < 4; hh++) {
                float l = asr[nb * 4 + hh] + adtv[hh];
                l = (l > 0.f) ? l : 0.2f * l;          // leaky_relu 0.2
                lg[e][hh] = l;
                mx[hh] = fmaxf(mx[hh], l);
            }
        }
        float sum[4] = { 0, 0, 0, 0 };
        float acc[16];
#pragma unroll
        for (int c = 0; c < 16; c++) acc[c] = 0.f;
#pragma unroll
        for (int e = 0; e < 9; e++) {
            long nb = bN + nbrs[e];
            const float4* xpn = (const float4*)&xp[nb * 16];
            float4 x0 = xpn[0], x1 = xpn[1], x2 = xpn[2], x3 = xpn[3];
            float xv[16] = { x0.x,x0.y,x0.z,x0.w, x1.x,x1.y,x1.z,x1.w,
                             x2.x,x2.y,x2.z,x2.w, x3.x,x3.y,x3.z,x3.w };
            float wv[4];
#pragma unroll
            for (int hh = 0; hh < 4; hh++) {
                float w2 = expf(lg[e][hh] - mx[hh]);
                sum[hh] += w2; wv[hh] = w2;
            }
#pragma unroll
            for (int hh = 0; hh < 4; hh++)
#pragma unroll
                for (int f = 0; f < 4; f++)
                    acc[hh * 4 + f] += wv[hh] * xv[hh * 4 + f];
        }
#pragma unroll
        for (int hh = 0; hh < 4; hh++) {
            float inv = 1.f / sum[hh];
#pragma unroll
            for (int f = 0; f < 4; f++) {
                float o = acc[hh * 4 + f] * inv + bg[hh * 4 + f];
                pshare[ns][hh * 4 + f] = fmaxf(o, 0.f);   // GAT relu -> LDS (p dead)
            }
        }
    }
    __syncthreads();
    // ---- fused update-MLP: all lanes; lane (ns, q) = node ns, hd quarter q
    float pv[16];
#pragma unroll
    for (int c = 0; c < 16; c++) pv[c] = pshare[ns][c];
    float u[16];
#pragma unroll
    for (int c = 0; c < 16; c++) u[c] = 0.f;
    int hd0 = q * 32;
    for (int hd = hd0; hd < hd0 + 32; hd++) {        // wave-uniform LDS addrs: broadcast
        const float4* r = (const float4*)&sU1[hd * 16];
        float4 w0 = r[0], w1 = r[1], w2 = r[2], w3 = r[3];
        float a = sb1[hd]
            + w0.x*pv[0] + w0.y*pv[1] + w0.z*pv[2] + w0.w*pv[3]
            + w1.x*pv[4] + w1.y*pv[5] + w1.z*pv[6] + w1.w*pv[7]
            + w2.x*pv[8] + w2.y*pv[9] + w2.z*pv[10]+ w2.w*pv[11]
            + w3.x*pv[12]+ w3.y*pv[13]+ w3.z*pv[14]+ w3.w*pv[15];
        a = fmaxf(a, 0.f);
        const float4* tt = (const float4*)&sU2t[hd * 16];
        float4 t0 = tt[0], t1 = tt[1], t2 = tt[2], t3 = tt[3];
        u[0] += t0.x*a; u[1] += t0.y*a; u[2] += t0.z*a; u[3] += t0.w*a;
        u[4] += t1.x*a; u[5] += t1.y*a; u[6] += t1.z*a; u[7] += t1.w*a;
        u[8] += t2.x*a; u[9] += t2.y*a; u[10]+= t2.z*a; u[11]+= t2.w*a;
        u[12]+= t3.x*a; u[13]+= t3.y*a; u[14]+= t3.z*a; u[15]+= t3.w*a;
    }
    // butterfly-reduce the 4 quarter-partials (fp32 reorder class)
#pragma unroll
    for (int c = 0; c < 16; c++) {
        u[c] += __shfl_xor(u[c], 16);
        u[c] += __shfl_xor(u[c], 32);
    }
    if (q == 0) {
        float mask = (fire[t] < 0.5f) ? 1.f : 0.f;
        float o = bo[0];
#pragma unroll
        for (int c = 0; c < 16; c++)
            o += Wo[c] * (ni[c] + mask * (u[c] + bu2[c]));   // ni == h[t]
        out_low[t] = 1.f / (1.f + expf(-o));
    }
}

// ---------------- bilinear upsample 64 -> 256 (half-pixel, clamp) -----------
// (validated R13; unchanged)
__launch_bounds__(256)
__global__ void k_up(const float* __restrict__ ol, float* __restrict__ out) {
    int idx = blockIdx.x * 256 + threadIdx.x;      // 0..131071 (4 pixels each)
    int b = idx >> 14, rem = idx & 16383;
    int oy = rem >> 6, ox0 = (rem & 63) * 4;
    float cy = (oy + 0.5f) * 0.25f - 0.5f;
    int iy0 = (int)floorf(cy); float fy = cy - (float)iy0;
    int y0 = min(max(iy0, 0), 63), y1 = min(max(iy0 + 1, 0), 63);
    const float* s = ol + b * NN;
    float res[4];
#pragma unroll
    for (int e = 0; e < 4; e++) {
        int ox = ox0 + e;
        float cx = (ox + 0.5f) * 0.25f - 0.5f;
        int ix0 = (int)floorf(cx); float fx = cx - (float)ix0;
        int x0 = min(max(ix0, 0), 63), x1 = min(max(ix0 + 1, 0), 63);
        res[e] = (1.f - fy) * ((1.f - fx) * s[y0 * 64 + x0] + fx * s[y0 * 64 + x1])
               + fy * ((1.f - fx) * s[y1 * 64 + x0] + fx * s[y1 * 64 + x1]);
    }
    *(float4*)&out[(long)idx * 4] = make_float4(res[0], res[1], res[2], res[3]);
}

extern "C" void kernel_launch(void* const* d_in, const int* in_sizes, int n_in,
                              void* d_out, int out_size, void* d_ws, size_t ws_size,
                              hipStream_t stream) {
    const float* x    = (const float*)d_in[0];
    const float* fire = (const float*)d_in[1];
    const float* W1   = (const float*)d_in[2];
    const float* b1   = (const float*)d_in[3];
    const float* g1   = (const float*)d_in[4];
    const float* be1  = (const float*)d_in[5];
    const float* m1   = (const float*)d_in[6];
    const float* v1   = (const float*)d_in[7];
    const float* W2   = (const float*)d_in[8];
    const float* b2   = (const float*)d_in[9];
    const float* g2   = (const float*)d_in[10];
    const float* be2  = (const float*)d_in[11];
    const float* m2   = (const float*)d_in[12];
    const float* v2   = (const float*)d_in[13];
    const float* Wg   = (const float*)d_in[14];
    const float* a_src= (const float*)d_in[15];
    const float* a_dst= (const float*)d_in[16];
    const float* bg   = (const float*)d_in[17];
    const float* Wu1  = (const float*)d_in[18];
    const float* bu1  = (const float*)d_in[19];
    const float* Wu2  = (const float*)d_in[20];
    const float* bu2  = (const float*)d_in[21];
    const float* Wo   = (const float*)d_in[22];
    const float* bo   = (const float*)d_in[23];

    float* ws  = (float*)d_ws;
    float* h1  = ws + OFF_H1;
    float* h   = ws + OFF_H;
    float* sq  = ws + OFF_SQ;
    float* xp  = ws + OFF_XP;
    float* asr = ws + OFF_ASR;
    float* adt = ws + OFF_ADT;
    float* ol  = ws + OFF_OL;
    // H1 region reuse (dead after conv2): cand_i 4 MB (NSL=8), bf16 splits,
    // nsq. Total 1,867,776 of 2,097,152 floats — no footprint growth.
    uint4*  cand_i = (uint4*)(ws + OFF_H1);
    ushort* hHi    = (ushort*)(ws + OFF_H1 + 1048576);
    ushort* hMid   = (ushort*)(ws + OFF_H1 + 1310720);
    ushort* hLo    = (ushort*)(ws + OFF_H1 + 1572864);
    float*  nsq    = ws + OFF_H1 + 1835008;

    k_dconv1<<<BATCH * 32, 512, 0, stream>>>(x, W1, b1, g1, be1, m1, v1, h1);
    k_conv2 <<<BATCH * 32, 512, 0, stream>>>(h1, W2, b2, g2, be2, m2, v2, Wg, a_src, a_dst,
                                             h, sq, xp, asr, adt);
    k_split <<<BATCH * NN / 256, 256, 0, stream>>>(h, sq, hHi, hMid, hLo, nsq);
    k_scan  <<<BATCH * 32 * NSL, 256, 0, stream>>>(hHi, hMid, hLo, nsq, cand_i);
    k_gat2  <<<BATCH * NN / 64, 256, 0, stream>>>(cand_i, h, sq, xp, asr, adt, bg,
                                                  fire, Wu1, bu1, Wu2, bu2, Wo, bo, ol);
    k_up    <<<(BATCH * HIGH * HIGH / 4) / 256, 256, 0, stream>>>(ol, (float*)d_out);
}